// Round 8
// baseline (120.238 us; speedup 1.0000x reference)
//
#include <hip/hip_runtime.h>
#include <stdint.h>

// N=M=16384, D=64 fp32. dist[n,m] = a_sq[n] + b_sq[m] - 2 a.b; out = sum_n min_m.
// Orientation: A(streamed) = TO points (K=80: dims 0..63, bsq at k=64),
// B(resident) = -2*FROM (K=64 + constant-1.0 ext fragment). C[row=to][col=from]
// -> per-lane min3-tree over 16 rows => 1 running min per col-subtile.
// Lessons: R6: dual A-buffer spills (unified VGPR+AGPR budget ~134 > 128 cap).
// R7: single-buffer, no spills, but MfmaUtil stuck at 34% -- lockstep waves
// convoy on the A-load wait. R8: stagger each wave's tile start by its wave
// index (phase-decorrelated, still L1-sharing) + interleave the two chains.
#define N_PTS 16384
#define KDIM_A 80
#define KDIM_B 64
#define TSPLITS 32
#define NBLOCKS (256 * TSPLITS / 4)  // 2048: 256 fg-groups x 32 splits / 4 waves
#define TO_CHUNK (N_PTS / TSPLITS)   // 512 TO pts per wave
#define TO_TILES (TO_CHUNK / 32)     // 16 tiles of 32 TO pts

typedef __attribute__((ext_vector_type(8)))  short bf16x8;
typedef __attribute__((ext_vector_type(16))) float f32x16;

__device__ __forceinline__ unsigned short f2bf(float f) {
    unsigned u = __float_as_uint(f);
    u += 0x7FFFu + ((u >> 16) & 1u);   // RNE
    return (unsigned short)(u >> 16);
}
__device__ __forceinline__ float tree16(f32x16 a) {
    float m0 = fminf(fminf(a[0],  a[1]),  a[2]);
    float m1 = fminf(fminf(a[3],  a[4]),  a[5]);
    float m2 = fminf(fminf(a[6],  a[7]),  a[8]);
    float m3 = fminf(fminf(a[9],  a[10]), a[11]);
    float m4 = fminf(fminf(a[12], a[13]), a[14]);
    float m5 = fminf(fminf(a[15], m0), m1);
    return fminf(fminf(fminf(m2, m3), m4), m5);
}

// ---------- prep: fp32 -> bf16 operands + norms (coalesced, 8 thr/row) ----
__global__ __launch_bounds__(256) void prep_kernel(
        const float* __restrict__ from_pts, const float* __restrict__ to_pts,
        float* __restrict__ a_sq, unsigned short* __restrict__ Bfrom,
        unsigned short* __restrict__ Ato, float* __restrict__ out) {
    int gid = blockIdx.x * 256 + threadIdx.x;   // 0 .. 262143
    int row = gid >> 3;                 // 0..32767 (FROM then TO)
    int sub = gid & 7;                  // 8 threads per row
    bool isFrom = row < N_PTS;
    int r = row & (N_PTS - 1);
    const float* src = isFrom ? from_pts : to_pts;
    float4 v0 = ((const float4*)src)[r * 16 + sub * 2];
    float4 v1 = ((const float4*)src)[r * 16 + sub * 2 + 1];
    float s = v0.x*v0.x + v0.y*v0.y + v0.z*v0.z + v0.w*v0.w
            + v1.x*v1.x + v1.y*v1.y + v1.z*v1.z + v1.w*v1.w;
    s += __shfl_xor(s, 1); s += __shfl_xor(s, 2); s += __shfl_xor(s, 4);
    float sc = isFrom ? -2.0f : 1.0f;
    union { unsigned short u[8]; uint4 q; } w;
    w.u[0] = f2bf(v0.x * sc); w.u[1] = f2bf(v0.y * sc);
    w.u[2] = f2bf(v0.z * sc); w.u[3] = f2bf(v0.w * sc);
    w.u[4] = f2bf(v1.x * sc); w.u[5] = f2bf(v1.y * sc);
    w.u[6] = f2bf(v1.z * sc); w.u[7] = f2bf(v1.w * sc);
    if (isFrom) {
        *(uint4*)(Bfrom + (size_t)r * KDIM_B + sub * 8) = w.q;
        if (sub == 0) a_sq[r] = s;
    } else {
        *(uint4*)(Ato + (size_t)r * KDIM_A + sub * 8) = w.q;
        if (sub == 0) {                 // ext block: bsq at k=64, zeros after
            uint4 z = {0u, 0u, 0u, 0u};
            uint4 e = z;
            e.x = (unsigned)f2bf(s);
            *(uint4*)(Ato + (size_t)r * KDIM_A + 64) = e;
            *(uint4*)(Ato + (size_t)r * KDIM_A + 72) = z;
        }
    }
    if (gid == 0) out[0] = 0.0f;        // replaces a separate memset node
}

// Two independent MFMA chains explicitly interleaved (2-deep ILP on the
// matrix pipe; dependent-MFMA latency hidden by the sibling chain).
#define CHAIN2(X)                                                               \
    {                                                                           \
        f32x16 acc0 = __builtin_amdgcn_mfma_f32_32x32x16_bf16(X[0], Bf0[0], zero, 0, 0, 0); \
        f32x16 acc1 = __builtin_amdgcn_mfma_f32_32x32x16_bf16(X[0], Bf1[0], zero, 0, 0, 0); \
        acc0 = __builtin_amdgcn_mfma_f32_32x32x16_bf16(X[1], Bf0[1], acc0, 0, 0, 0); \
        acc1 = __builtin_amdgcn_mfma_f32_32x32x16_bf16(X[1], Bf1[1], acc1, 0, 0, 0); \
        acc0 = __builtin_amdgcn_mfma_f32_32x32x16_bf16(X[2], Bf0[2], acc0, 0, 0, 0); \
        acc1 = __builtin_amdgcn_mfma_f32_32x32x16_bf16(X[2], Bf1[2], acc1, 0, 0, 0); \
        acc0 = __builtin_amdgcn_mfma_f32_32x32x16_bf16(X[3], Bf0[3], acc0, 0, 0, 0); \
        acc1 = __builtin_amdgcn_mfma_f32_32x32x16_bf16(X[3], Bf1[3], acc1, 0, 0, 0); \
        acc0 = __builtin_amdgcn_mfma_f32_32x32x16_bf16(X[4], Bext, acc0, 0, 0, 0); \
        acc1 = __builtin_amdgcn_mfma_f32_32x32x16_bf16(X[4], Bext, acc1, 0, 0, 0); \
        rmin0 = fminf(rmin0, tree16(acc0));                                     \
        rmin1 = fminf(rmin1, tree16(acc1));                                     \
    }

// ---------- main: MFMA + in-lane min; plain stores to pmin[ts][row] -------
__global__ __launch_bounds__(256, 4) void main_kernel(
        const unsigned short* __restrict__ Bfrom,
        const unsigned short* __restrict__ Ato,
        float* __restrict__ pmin) {
    const int tid = threadIdx.x;
    const int lane = tid & 63;
    const int l31 = lane & 31;
    const int h   = lane >> 5;
    const int wid = (blockIdx.x << 2) + (tid >> 6);   // 0..8191
    const int fg  = wid & 255;          // 64 FROM pts per wave
    const int ts  = wid >> 8;           // block's 4 waves: same ts
    const int woff = (tid >> 6) & 3;    // per-wave tile phase offset (anti-convoy)

    // resident FROM fragments, 2 col-subtiles x 4 k-blocks
    bf16x8 Bf0[4], Bf1[4];
    {
        const unsigned short* br = Bfrom + (size_t)(fg * 64 + l31) * KDIM_B + h * 8;
        #pragma unroll
        for (int kb = 0; kb < 4; kb++) {
            Bf0[kb] = *(const bf16x8*)(br + kb * 16);
            Bf1[kb] = *(const bf16x8*)(br + 32 * KDIM_B + kb * 16);
        }
    }
    // constant B ext fragment: B[n][k=64] = 1.0 (h==0, j==0 slot)
    bf16x8 Bext;
    #pragma unroll
    for (int j = 0; j < 8; j++) Bext[j] = 0;
    if (h == 0) Bext[0] = (short)0x3F80;

    f32x16 zero;
    #pragma unroll
    for (int r = 0; r < 16; r++) zero[r] = 0.0f;

    float rmin0 = 3.0e38f, rmin1 = 3.0e38f;
    const unsigned short* ab = Ato + (size_t)(ts * TO_CHUNK + l31) * KDIM_A + h * 8;

    #pragma unroll 1
    for (int t = 0; t < TO_TILES; t++) {
        int tt = (t + woff) & (TO_TILES - 1);   // staggered tile order
        const unsigned short* at = ab + (size_t)tt * 32 * KDIM_A;
        bf16x8 Ac[5];
        #pragma unroll
        for (int kb = 0; kb < 5; kb++) Ac[kb] = *(const bf16x8*)(at + kb * 16);
        CHAIN2(Ac)
    }

    // cross-half min, then plain store: (ts,fg) is wave-unique -> no atomics
    rmin0 = fminf(rmin0, __shfl_xor(rmin0, 32));
    rmin1 = fminf(rmin1, __shfl_xor(rmin1, 32));
    if (lane < 32) {
        pmin[(size_t)ts * N_PTS + fg * 64 + l31]      = rmin0;
        pmin[(size_t)ts * N_PTS + fg * 64 + 32 + l31] = rmin1;
    }
}

// ---------- finish: min over 32 splits, add a_sq, global sum --------------
__global__ __launch_bounds__(256) void finish_kernel(
        const float* __restrict__ a_sq, const float* __restrict__ pmin,
        float* __restrict__ out) {
    int r = blockIdx.x * 256 + threadIdx.x;
    float m = pmin[r];
    #pragma unroll
    for (int s = 1; s < TSPLITS; s++)
        m = fminf(m, pmin[(size_t)s * N_PTS + r]);
    float v = a_sq[r] + m;
    #pragma unroll
    for (int k = 1; k < 64; k <<= 1) v += __shfl_xor(v, k);
    __shared__ float red[4];
    if ((threadIdx.x & 63) == 0) red[threadIdx.x >> 6] = v;
    __syncthreads();
    if (threadIdx.x == 0)
        atomicAdd(out, red[0] + red[1] + red[2] + red[3]);
}

extern "C" void kernel_launch(void* const* d_in, const int* in_sizes, int n_in,
                              void* d_out, int out_size, void* d_ws, size_t ws_size,
                              hipStream_t stream) {
    const float* from_pts = (const float*)d_in[0];
    const float* to_pts   = (const float*)d_in[1];
    char* ws = (char*)d_ws;
    float*          a_sq  = (float*)ws;                                //   64 KB
    float*          pmin  = (float*)(ws + (64 << 10));                 //    2 MB
    unsigned short* Bfrom = (unsigned short*)(ws + (64 << 10) + (2 << 20));           // 2 MB
    unsigned short* Ato   = (unsigned short*)(ws + (64 << 10) + (2 << 20) + (2 << 20)); // 2.56 MB

    prep_kernel<<<(2 * N_PTS * 8) / 256, 256, 0, stream>>>(from_pts, to_pts,
                                                           a_sq, Bfrom, Ato,
                                                           (float*)d_out);
    main_kernel<<<NBLOCKS, 256, 0, stream>>>(Bfrom, Ato, pmin);
    finish_kernel<<<N_PTS / 256, 256, 0, stream>>>(a_sq, pmin, (float*)d_out);
}

// Round 9
// 103.813 us; speedup vs baseline: 1.1582x; 1.1582x over previous
//
#include <hip/hip_runtime.h>
#include <stdint.h>

// N=M=16384, D=64 fp32. dist[n,m] = a_sq[n] + b_sq[m] - 2 a.b; out = sum_n min_m.
// A(streamed) = TO pts, B(resident) = -2*FROM. C[row=to][col=from]: min over
// rows is IN-LANE (tree16) -> 1 running min per col-subtile.
// R8 lesson: row-major operand storage made every MFMA A-load a 64-way
// scattered gather (64 lines/inst) -- the ~2500-cyc/tile stall behind
// MfmaUtil<=34%. R9: prep writes operands in FRAGMENT order (AtoF[tile][kb]
// [lane]) -> every A-load is one coalesced 1KB transaction; b_sq enters via
// fp32 cinit (permuted bsqp, broadcast loads) instead of a 5th K-ext MFMA.
#define N_PTS 16384
#define TSPLITS 32
#define NBLOCKS (256 * TSPLITS / 4)  // 2048 blocks, 4 waves each
#define TO_CHUNK (N_PTS / TSPLITS)   // 512 TO pts per wave
#define TO_TILES (TO_CHUNK / 32)     // 16 tiles of 32 TO pts

typedef __attribute__((ext_vector_type(8)))  short bf16x8;
typedef __attribute__((ext_vector_type(16))) float f32x16;

__device__ __forceinline__ unsigned short f2bf(float f) {
    unsigned u = __float_as_uint(f);
    u += 0x7FFFu + ((u >> 16) & 1u);   // RNE
    return (unsigned short)(u >> 16);
}
__device__ __forceinline__ float tree16(f32x16 a) {
    float m0 = fminf(fminf(a[0],  a[1]),  a[2]);
    float m1 = fminf(fminf(a[3],  a[4]),  a[5]);
    float m2 = fminf(fminf(a[6],  a[7]),  a[8]);
    float m3 = fminf(fminf(a[9],  a[10]), a[11]);
    float m4 = fminf(fminf(a[12], a[13]), a[14]);
    float m5 = fminf(fminf(a[15], m0), m1);
    return fminf(fminf(fminf(m2, m3), m4), m5);
}

// ---------- prep: fp32 -> bf16 FRAGMENT-ORDER operands + norms ------------
// thread (row, sub): sub owns dims sub*8..sub*8+7 = fragment (kb=sub>>1,
// h=sub&1). Reads stay fully coalesced; writes scatter 16B (fire-and-forget).
__global__ __launch_bounds__(256) void prep_kernel(
        const float* __restrict__ from_pts, const float* __restrict__ to_pts,
        float* __restrict__ a_sq, float* __restrict__ bsqp,
        unsigned short* __restrict__ BfF, unsigned short* __restrict__ AtoF,
        float* __restrict__ out) {
    int gid = blockIdx.x * 256 + threadIdx.x;   // 0 .. 262143
    int row = gid >> 3;                 // 0..32767 (FROM then TO)
    int sub = gid & 7;
    bool isFrom = row < N_PTS;
    int r = row & (N_PTS - 1);
    const float* src = isFrom ? from_pts : to_pts;
    float4 v0 = ((const float4*)src)[r * 16 + sub * 2];
    float4 v1 = ((const float4*)src)[r * 16 + sub * 2 + 1];
    float s = v0.x*v0.x + v0.y*v0.y + v0.z*v0.z + v0.w*v0.w
            + v1.x*v1.x + v1.y*v1.y + v1.z*v1.z + v1.w*v1.w;
    s += __shfl_xor(s, 1); s += __shfl_xor(s, 2); s += __shfl_xor(s, 4);
    float sc = isFrom ? -2.0f : 1.0f;
    union { unsigned short u[8]; uint4 q; } w;
    w.u[0] = f2bf(v0.x * sc); w.u[1] = f2bf(v0.y * sc);
    w.u[2] = f2bf(v0.z * sc); w.u[3] = f2bf(v0.w * sc);
    w.u[4] = f2bf(v1.x * sc); w.u[5] = f2bf(v1.y * sc);
    w.u[6] = f2bf(v1.z * sc); w.u[7] = f2bf(v1.w * sc);
    int st = r >> 5;                    // subtile / tile index (0..511)
    int m  = r & 31;
    int kb = sub >> 1, h = sub & 1;
    size_t fidx = (((size_t)st * 4 + kb) * 64 + h * 32 + m) * 8;
    if (isFrom) {
        *(uint4*)(BfF + fidx) = w.q;
        if (sub == 0) a_sq[r] = s;
    } else {
        *(uint4*)(AtoF + fidx) = w.q;
        // bsq in C/D-layout order: reg=(m&3)+4*(m>>3), h-half=(m>>2)&1
        if (sub == 0)
            bsqp[st * 32 + ((m >> 2) & 1) * 16 + (m & 3) + 4 * (m >> 3)] = s;
    }
    if (gid == 0) out[0] = 0.0f;
}

// ---------- main: coalesced fragment loads + MFMA + in-lane min -----------
// ~100 regs (Bf 32, Ac 16, cin 16, acc 16, few addr/temps): fits (256,4)'s
// 128 cap with headroom -> no spills. All 16 waves/CU read the same A-tile
// addresses (same ts on a CU) -> L1 broadcast.
__global__ __launch_bounds__(256, 4) void main_kernel(
        const unsigned short* __restrict__ BfF,
        const unsigned short* __restrict__ AtoF,
        const float* __restrict__ bsqp, float* __restrict__ pmin) {
    const int tid = threadIdx.x;
    const int lane = tid & 63;
    const int l31 = lane & 31;
    const int h   = lane >> 5;
    const int wid = (blockIdx.x << 2) + (tid >> 6);   // 0..8191
    const int fg  = wid & 255;          // 64 FROM pts per wave
    const int ts  = wid >> 8;           // 0..31; block's 4 waves: same ts

    const bf16x8* Bv = (const bf16x8*)BfF;
    const bf16x8* Av = (const bf16x8*)AtoF;

    // resident FROM fragments: subtiles st0=2*fg, st1=2*fg+1 (coalesced)
    bf16x8 Bf0[4], Bf1[4];
    #pragma unroll
    for (int kb = 0; kb < 4; kb++) {
        Bf0[kb] = Bv[((size_t)(2 * fg)     * 4 + kb) * 64 + lane];
        Bf1[kb] = Bv[((size_t)(2 * fg + 1) * 4 + kb) * 64 + lane];
    }

    float rmin0 = 3.0e38f, rmin1 = 3.0e38f;

    #pragma unroll 1
    for (int t = 0; t < TO_TILES; t++) {
        const int gt = ts * TO_TILES + t;
        // A-tile: 4 coalesced 1KB loads (lane-linear fragment order)
        bf16x8 Ac[4];
        #pragma unroll
        for (int kb = 0; kb < 4; kb++)
            Ac[kb] = Av[((size_t)gt * 4 + kb) * 64 + lane];
        // cinit = b_sq of this tile's 16 rows for this half (broadcast 64B)
        const float4* cp = (const float4*)(bsqp + gt * 32 + h * 16);
        float4 c0 = cp[0], c1 = cp[1], c2 = cp[2], c3 = cp[3];
        f32x16 cin;
        cin[0] = c0.x; cin[1] = c0.y; cin[2]  = c0.z; cin[3]  = c0.w;
        cin[4] = c1.x; cin[5] = c1.y; cin[6]  = c1.z; cin[7]  = c1.w;
        cin[8] = c2.x; cin[9] = c2.y; cin[10] = c2.z; cin[11] = c2.w;
        cin[12] = c3.x; cin[13] = c3.y; cin[14] = c3.z; cin[15] = c3.w;

        f32x16 acc0 = __builtin_amdgcn_mfma_f32_32x32x16_bf16(Ac[0], Bf0[0], cin, 0, 0, 0);
        acc0 = __builtin_amdgcn_mfma_f32_32x32x16_bf16(Ac[1], Bf0[1], acc0, 0, 0, 0);
        acc0 = __builtin_amdgcn_mfma_f32_32x32x16_bf16(Ac[2], Bf0[2], acc0, 0, 0, 0);
        acc0 = __builtin_amdgcn_mfma_f32_32x32x16_bf16(Ac[3], Bf0[3], acc0, 0, 0, 0);
        rmin0 = fminf(rmin0, tree16(acc0));

        f32x16 acc1 = __builtin_amdgcn_mfma_f32_32x32x16_bf16(Ac[0], Bf1[0], cin, 0, 0, 0);
        acc1 = __builtin_amdgcn_mfma_f32_32x32x16_bf16(Ac[1], Bf1[1], acc1, 0, 0, 0);
        acc1 = __builtin_amdgcn_mfma_f32_32x32x16_bf16(Ac[2], Bf1[2], acc1, 0, 0, 0);
        acc1 = __builtin_amdgcn_mfma_f32_32x32x16_bf16(Ac[3], Bf1[3], acc1, 0, 0, 0);
        rmin1 = fminf(rmin1, tree16(acc1));
    }

    // cross-half min, then plain store: (ts,fg) is wave-unique -> no atomics
    rmin0 = fminf(rmin0, __shfl_xor(rmin0, 32));
    rmin1 = fminf(rmin1, __shfl_xor(rmin1, 32));
    if (lane < 32) {
        pmin[(size_t)ts * N_PTS + fg * 64 + l31]      = rmin0;
        pmin[(size_t)ts * N_PTS + fg * 64 + 32 + l31] = rmin1;
    }
}

// ---------- finish: min over 32 splits, add a_sq, global sum --------------
__global__ __launch_bounds__(256) void finish_kernel(
        const float* __restrict__ a_sq, const float* __restrict__ pmin,
        float* __restrict__ out) {
    int r = blockIdx.x * 256 + threadIdx.x;
    float m = pmin[r];
    #pragma unroll
    for (int s = 1; s < TSPLITS; s++)
        m = fminf(m, pmin[(size_t)s * N_PTS + r]);
    float v = a_sq[r] + m;
    #pragma unroll
    for (int k = 1; k < 64; k <<= 1) v += __shfl_xor(v, k);
    __shared__ float red[4];
    if ((threadIdx.x & 63) == 0) red[threadIdx.x >> 6] = v;
    __syncthreads();
    if (threadIdx.x == 0)
        atomicAdd(out, red[0] + red[1] + red[2] + red[3]);
}

extern "C" void kernel_launch(void* const* d_in, const int* in_sizes, int n_in,
                              void* d_out, int out_size, void* d_ws, size_t ws_size,
                              hipStream_t stream) {
    const float* from_pts = (const float*)d_in[0];
    const float* to_pts   = (const float*)d_in[1];
    char* ws = (char*)d_ws;
    float*          a_sq = (float*)ws;                                 //  64 KB
    float*          bsqp = (float*)(ws + (64 << 10));                  //  64 KB
    float*          pmin = (float*)(ws + (128 << 10));                 //   2 MB
    unsigned short* BfF  = (unsigned short*)(ws + (128 << 10) + (2 << 20));           // 2 MB
    unsigned short* AtoF = (unsigned short*)(ws + (128 << 10) + (2 << 20) + (2 << 20)); // 2 MB

    prep_kernel<<<(2 * N_PTS * 8) / 256, 256, 0, stream>>>(
        from_pts, to_pts, a_sq, bsqp, BfF, AtoF, (float*)d_out);
    main_kernel<<<NBLOCKS, 256, 0, stream>>>(BfF, AtoF, bsqp, pmin);
    finish_kernel<<<N_PTS / 256, 256, 0, stream>>>(a_sq, pmin, (float*)d_out);
}